// Round 1
// baseline (1043.402 us; speedup 1.0000x reference)
//
#include <hip/hip_runtime.h>

// CustomAttention: x[2,2048,1024] f32, w_qkv[3072,1024], w_proj[1024,1024], b_proj[1024]
// out[2,2048,1024] f32.
// Round 1: all-f32 correctness baseline.
//   k1: qkv gemm (M=4096, N=3072, K=1024) -> scatter Q(scaled)/K/V [b,h,n,d] in ws
//   k2: flash attention, 1 block per (b*h, 64 q rows), 256 thr, 4x4 micro
//   k3: proj gemm (M=4096, N=1024, K=1024) + bias -> d_out

constexpr int B_ = 2, N_ = 2048, C_ = 1024, H_ = 16, D_ = 64;
constexpr int M_ = B_ * N_;   // 4096
constexpr int O3 = 3 * C_;    // 3072

// XOR-swizzled k-major 64x64 tile index (float units). Keeps float4 reads
// aligned (swizzle in 4-float granules) and transpose-stores ~2-way.
__device__ __forceinline__ int tr_idx(int row, int col) {
    return row * 64 + ((((col >> 2) ^ (row >> 2)) & 15) << 2) + (col & 3);
}

// ---------------- QKV GEMM ----------------
__global__ __launch_bounds__(256)
void qkv_gemm(const float* __restrict__ A, const float* __restrict__ W,
              float* __restrict__ Qd, float* __restrict__ Kd, float* __restrict__ Vd)
{
    __shared__ __align__(16) float As[16][128];
    __shared__ __align__(16) float Bs[16][128];
    const int t  = threadIdx.x;
    const int tr = t >> 4, tc = t & 15;
    const int bm = blockIdx.y * 128;
    const int bn = blockIdx.x * 128;
    constexpr int K = C_;

    float acc[8][8];
    #pragma unroll
    for (int i = 0; i < 8; ++i)
        #pragma unroll
        for (int j = 0; j < 8; ++j) acc[i][j] = 0.f;

    for (int k0 = 0; k0 < K; k0 += 16) {
        #pragma unroll
        for (int qq = 0; qq < 2; ++qq) {
            int id = t + qq * 256;        // 0..511
            int r  = id >> 2;             // 0..127
            int c4 = (id & 3) << 2;       // 0,4,8,12
            float4 va = *(const float4*)(A + (size_t)(bm + r) * K + k0 + c4);
            As[c4+0][r] = va.x; As[c4+1][r] = va.y; As[c4+2][r] = va.z; As[c4+3][r] = va.w;
            float4 vb = *(const float4*)(W + (size_t)(bn + r) * K + k0 + c4);
            Bs[c4+0][r] = vb.x; Bs[c4+1][r] = vb.y; Bs[c4+2][r] = vb.z; Bs[c4+3][r] = vb.w;
        }
        __syncthreads();
        #pragma unroll
        for (int kk = 0; kk < 16; ++kk) {
            float4 a0 = *(const float4*)&As[kk][tr << 2];
            float4 a1 = *(const float4*)&As[kk][64 + (tr << 2)];
            float4 b0 = *(const float4*)&Bs[kk][tc << 2];
            float4 b1 = *(const float4*)&Bs[kk][64 + (tc << 2)];
            float ar[8] = {a0.x,a0.y,a0.z,a0.w,a1.x,a1.y,a1.z,a1.w};
            float br[8] = {b0.x,b0.y,b0.z,b0.w,b1.x,b1.y,b1.z,b1.w};
            #pragma unroll
            for (int i = 0; i < 8; ++i)
                #pragma unroll
                for (int j = 0; j < 8; ++j) acc[i][j] = fmaf(ar[i], br[j], acc[i][j]);
        }
        __syncthreads();
    }

    // scatter epilogue: o = which*1024 + h*64 + d; q scaled by D^-0.5
    #pragma unroll
    for (int ih = 0; ih < 2; ++ih)
        #pragma unroll
        for (int jh = 0; jh < 2; ++jh) {
            int o0 = bn + jh * 64 + (tc << 2);
            int which = o0 >> 10;
            int oo = o0 & 1023;
            int h = oo >> 6, d0 = oo & 63;
            float* dst = (which == 0) ? Qd : (which == 1) ? Kd : Vd;
            float sc = (which == 0) ? 0.125f : 1.0f;
            #pragma unroll
            for (int i = 0; i < 4; ++i) {
                int m = bm + ih * 64 + (tr << 2) + i;
                int b = m >> 11, n = m & 2047;
                float4 v;
                v.x = acc[ih*4+i][jh*4+0] * sc;
                v.y = acc[ih*4+i][jh*4+1] * sc;
                v.z = acc[ih*4+i][jh*4+2] * sc;
                v.w = acc[ih*4+i][jh*4+3] * sc;
                *(float4*)&dst[(((size_t)b * H_ + h) * N_ + n) * D_ + d0] = v;
            }
        }
}

// ---------------- Flash attention ----------------
__global__ __launch_bounds__(256)
void attn_fwd(const float* __restrict__ Q, const float* __restrict__ K,
              const float* __restrict__ V, float* __restrict__ AO)
{
    __shared__ __align__(16) float Qt[64 * 64];   // k-major, swizzled
    __shared__ __align__(16) float Kt[64 * 64];   // k-major, swizzled
    __shared__ __align__(16) float Pt[64 * 64];   // [score_col][q_row], swizzled
    __shared__ __align__(16) float Vs[64][64];    // natural [j][d]

    const int t  = threadIdx.x;
    const int tr = t >> 4, tc = t & 15;
    const int bh = blockIdx.y;              // b*16 + h
    const int b  = bh >> 4, h = bh & 15;
    const int q0 = blockIdx.x * 64;

    const float* Qp = Q + (size_t)bh * N_ * D_;
    const float* Kp = K + (size_t)bh * N_ * D_;
    const float* Vp = V + (size_t)bh * N_ * D_;

    // stage Q tile (transposed+swizzled); Q is already pre-scaled
    #pragma unroll
    for (int qq = 0; qq < 4; ++qq) {
        int id = t + qq * 256;
        int r  = id >> 4;            // 0..63
        int c4 = (id & 15) << 2;     // k offset
        float4 v = *(const float4*)(Qp + (size_t)(q0 + r) * D_ + c4);
        Qt[tr_idx(c4+0, r)] = v.x;
        Qt[tr_idx(c4+1, r)] = v.y;
        Qt[tr_idx(c4+2, r)] = v.z;
        Qt[tr_idx(c4+3, r)] = v.w;
    }

    float m_run[4], l_run[4], Oac[4][4];
    #pragma unroll
    for (int i = 0; i < 4; ++i) {
        m_run[i] = -1e30f; l_run[i] = 0.f;
        #pragma unroll
        for (int j = 0; j < 4; ++j) Oac[i][j] = 0.f;
    }

    for (int kt = 0; kt < N_ / 64; ++kt) {
        __syncthreads();   // prior-iteration readers of Kt/Vs/Pt are done
        #pragma unroll
        for (int qq = 0; qq < 4; ++qq) {
            int id = t + qq * 256;
            int r  = id >> 4;
            int c4 = (id & 15) << 2;
            float4 kv = *(const float4*)(Kp + (size_t)(kt * 64 + r) * D_ + c4);
            Kt[tr_idx(c4+0, r)] = kv.x;
            Kt[tr_idx(c4+1, r)] = kv.y;
            Kt[tr_idx(c4+2, r)] = kv.z;
            Kt[tr_idx(c4+3, r)] = kv.w;
            float4 vv = *(const float4*)(Vp + (size_t)(kt * 64 + r) * D_ + c4);
            *(float4*)&Vs[r][c4] = vv;
        }
        __syncthreads();

        // S = Q K^T (rows tr*4+i, cols tc*4+j)
        float s[4][4];
        #pragma unroll
        for (int i = 0; i < 4; ++i)
            #pragma unroll
            for (int j = 0; j < 4; ++j) s[i][j] = 0.f;
        #pragma unroll 16
        for (int kk = 0; kk < 64; ++kk) {
            float4 qa = *(const float4*)&Qt[tr_idx(kk, tr << 2)];
            float4 kb = *(const float4*)&Kt[tr_idx(kk, tc << 2)];
            float ar[4] = {qa.x, qa.y, qa.z, qa.w};
            float br[4] = {kb.x, kb.y, kb.z, kb.w};
            #pragma unroll
            for (int i = 0; i < 4; ++i)
                #pragma unroll
                for (int j = 0; j < 4; ++j) s[i][j] = fmaf(ar[i], br[j], s[i][j]);
        }

        // online softmax (row reduce over 16 lanes sharing tr)
        #pragma unroll
        for (int i = 0; i < 4; ++i) {
            float mx = fmaxf(fmaxf(s[i][0], s[i][1]), fmaxf(s[i][2], s[i][3]));
            #pragma unroll
            for (int off = 1; off < 16; off <<= 1) mx = fmaxf(mx, __shfl_xor(mx, off));
            float nm = fmaxf(m_run[i], mx);
            float corr = __expf(m_run[i] - nm);
            float rs = 0.f;
            #pragma unroll
            for (int j = 0; j < 4; ++j) { float p = __expf(s[i][j] - nm); s[i][j] = p; rs += p; }
            #pragma unroll
            for (int off = 1; off < 16; off <<= 1) rs += __shfl_xor(rs, off);
            l_run[i] = l_run[i] * corr + rs;
            m_run[i] = nm;
            #pragma unroll
            for (int j = 0; j < 4; ++j) Oac[i][j] *= corr;
        }

        // stage P transposed: Pt[score_col][q_row]
        #pragma unroll
        for (int j = 0; j < 4; ++j) {
            float4 pv = make_float4(s[0][j], s[1][j], s[2][j], s[3][j]);
            *(float4*)&Pt[tr_idx((tc << 2) + j, tr << 2)] = pv;
        }
        __syncthreads();

        // O += P V (rows tr*4+i, d cols tc*4+j)
        #pragma unroll 16
        for (int jj = 0; jj < 64; ++jj) {
            float4 pa = *(const float4*)&Pt[tr_idx(jj, tr << 2)];
            float4 vb = *(const float4*)&Vs[jj][tc << 2];
            float pr[4] = {pa.x, pa.y, pa.z, pa.w};
            float vr[4] = {vb.x, vb.y, vb.z, vb.w};
            #pragma unroll
            for (int i = 0; i < 4; ++i)
                #pragma unroll
                for (int j = 0; j < 4; ++j) Oac[i][j] = fmaf(pr[i], vr[j], Oac[i][j]);
        }
    }

    // normalize + write [b, n, h*64+d]
    #pragma unroll
    for (int i = 0; i < 4; ++i) {
        float inv = 1.0f / l_run[i];
        float4 o = make_float4(Oac[i][0]*inv, Oac[i][1]*inv, Oac[i][2]*inv, Oac[i][3]*inv);
        int n = q0 + (tr << 2) + i;
        *(float4*)&AO[((size_t)b * N_ + n) * C_ + h * D_ + (tc << 2)] = o;
    }
}

// ---------------- Proj GEMM + bias ----------------
__global__ __launch_bounds__(256)
void proj_gemm(const float* __restrict__ A, const float* __restrict__ W,
               const float* __restrict__ bias, float* __restrict__ Out)
{
    __shared__ __align__(16) float As[16][128];
    __shared__ __align__(16) float Bs[16][128];
    const int t  = threadIdx.x;
    const int tr = t >> 4, tc = t & 15;
    const int bm = blockIdx.y * 128;
    const int bn = blockIdx.x * 128;
    constexpr int K = C_;

    float acc[8][8];
    #pragma unroll
    for (int i = 0; i < 8; ++i)
        #pragma unroll
        for (int j = 0; j < 8; ++j) acc[i][j] = 0.f;

    for (int k0 = 0; k0 < K; k0 += 16) {
        #pragma unroll
        for (int qq = 0; qq < 2; ++qq) {
            int id = t + qq * 256;
            int r  = id >> 2;
            int c4 = (id & 3) << 2;
            float4 va = *(const float4*)(A + (size_t)(bm + r) * K + k0 + c4);
            As[c4+0][r] = va.x; As[c4+1][r] = va.y; As[c4+2][r] = va.z; As[c4+3][r] = va.w;
            float4 vb = *(const float4*)(W + (size_t)(bn + r) * K + k0 + c4);
            Bs[c4+0][r] = vb.x; Bs[c4+1][r] = vb.y; Bs[c4+2][r] = vb.z; Bs[c4+3][r] = vb.w;
        }
        __syncthreads();
        #pragma unroll
        for (int kk = 0; kk < 16; ++kk) {
            float4 a0 = *(const float4*)&As[kk][tr << 2];
            float4 a1 = *(const float4*)&As[kk][64 + (tr << 2)];
            float4 b0 = *(const float4*)&Bs[kk][tc << 2];
            float4 b1 = *(const float4*)&Bs[kk][64 + (tc << 2)];
            float ar[8] = {a0.x,a0.y,a0.z,a0.w,a1.x,a1.y,a1.z,a1.w};
            float br[8] = {b0.x,b0.y,b0.z,b0.w,b1.x,b1.y,b1.z,b1.w};
            #pragma unroll
            for (int i = 0; i < 8; ++i)
                #pragma unroll
                for (int j = 0; j < 8; ++j) acc[i][j] = fmaf(ar[i], br[j], acc[i][j]);
        }
        __syncthreads();
    }

    #pragma unroll
    for (int ih = 0; ih < 2; ++ih)
        #pragma unroll
        for (int jh = 0; jh < 2; ++jh) {
            int o0 = bn + jh * 64 + (tc << 2);
            float4 bb = *(const float4*)&bias[o0];
            #pragma unroll
            for (int i = 0; i < 4; ++i) {
                int m = bm + ih * 64 + (tr << 2) + i;
                float4 v;
                v.x = acc[ih*4+i][jh*4+0] + bb.x;
                v.y = acc[ih*4+i][jh*4+1] + bb.y;
                v.z = acc[ih*4+i][jh*4+2] + bb.z;
                v.w = acc[ih*4+i][jh*4+3] + bb.w;
                *(float4*)&Out[(size_t)m * C_ + o0] = v;
            }
        }
}

extern "C" void kernel_launch(void* const* d_in, const int* in_sizes, int n_in,
                              void* d_out, int out_size, void* d_ws, size_t ws_size,
                              hipStream_t stream) {
    const float* x      = (const float*)d_in[0];
    const float* w_qkv  = (const float*)d_in[1];
    const float* w_proj = (const float*)d_in[2];
    const float* b_proj = (const float*)d_in[3];
    float* out = (float*)d_out;

    float* ws = (float*)d_ws;
    const size_t hd = (size_t)B_ * H_ * N_ * D_;   // 4,194,304 floats
    float* Qd = ws;
    float* Kd = Qd + hd;
    float* Vd = Kd + hd;
    float* AO = Vd + hd;                            // [B,N,C] f32

    qkv_gemm<<<dim3(O3 / 128, M_ / 128), 256, 0, stream>>>(x, w_qkv, Qd, Kd, Vd);
    attn_fwd<<<dim3(N_ / 64, B_ * H_), 256, 0, stream>>>(Qd, Kd, Vd, AO);
    proj_gemm<<<dim3(C_ / 128, M_ / 128), 256, 0, stream>>>(AO, w_proj, b_proj, out);
}

// Round 2
// 527.243 us; speedup vs baseline: 1.9790x; 1.9790x over previous
//
#include <hip/hip_runtime.h>

// CustomAttention: x[2,2048,1024] f32, w_qkv[3072,1024], w_proj[1024,1024], b_proj[1024]
// Round 2: MFMA bf16 flash attention; f32 SIMT GEMMs kept from round 1.
//   k1: qkv gemm f32 -> Qd bf16 [bh][n][d] (scaled by 0.125*log2e), Kd bf16 [bh][n][d],
//       Vt bf16 [bh][d][n] (pre-transposed for PV A-operand)
//   k2: attn_mfma: 4 waves x 16 q-rows, KV tiles of 64, 16x16x32 bf16 MFMA,
//       swapped QK^T (S^T), wave-private LDS P redistribution, out^T epilogue -> AO f32
//   k3: proj gemm f32 + bias -> d_out

constexpr int B_ = 2, N_ = 2048, C_ = 1024, H_ = 16, D_ = 64;
constexpr int M_ = B_ * N_;   // 4096
constexpr int O3 = 3 * C_;    // 3072
constexpr int KVB = 64;
constexpr int NTILES = N_ / KVB;   // 32

typedef short bf16x8 __attribute__((ext_vector_type(8)));
typedef float f32x4  __attribute__((ext_vector_type(4)));

__device__ __forceinline__ unsigned short f2bf(float f) {
    unsigned int u = __float_as_uint(f);
    unsigned int r = (u + 0x7FFFu + ((u >> 16) & 1u)) >> 16;
    return (unsigned short)r;
}

__device__ __forceinline__ void async16(const void* g, void* l) {
    __builtin_amdgcn_global_load_lds(
        (const __attribute__((address_space(1))) unsigned int*)g,
        (__attribute__((address_space(3))) unsigned int*)l, 16, 0, 0);
}

// ---------------- QKV GEMM (f32 SIMT) ----------------
__global__ __launch_bounds__(256)
void qkv_gemm(const float* __restrict__ A, const float* __restrict__ W,
              unsigned short* __restrict__ Qd, unsigned short* __restrict__ Kd,
              unsigned short* __restrict__ Vt)
{
    __shared__ __align__(16) float As[16][128];
    __shared__ __align__(16) float Bs[16][128];
    const int t  = threadIdx.x;
    const int tr = t >> 4, tc = t & 15;
    const int bm = blockIdx.y * 128;
    const int bn = blockIdx.x * 128;
    constexpr int K = C_;
    constexpr float QSCALE = 0.125f * 1.4426950408889634f;   // D^-0.5 * log2(e)

    float acc[8][8];
    #pragma unroll
    for (int i = 0; i < 8; ++i)
        #pragma unroll
        for (int j = 0; j < 8; ++j) acc[i][j] = 0.f;

    for (int k0 = 0; k0 < K; k0 += 16) {
        #pragma unroll
        for (int qq = 0; qq < 2; ++qq) {
            int id = t + qq * 256;
            int r  = id >> 2;
            int c4 = (id & 3) << 2;
            float4 va = *(const float4*)(A + (size_t)(bm + r) * K + k0 + c4);
            As[c4+0][r] = va.x; As[c4+1][r] = va.y; As[c4+2][r] = va.z; As[c4+3][r] = va.w;
            float4 vb = *(const float4*)(W + (size_t)(bn + r) * K + k0 + c4);
            Bs[c4+0][r] = vb.x; Bs[c4+1][r] = vb.y; Bs[c4+2][r] = vb.z; Bs[c4+3][r] = vb.w;
        }
        __syncthreads();
        #pragma unroll
        for (int kk = 0; kk < 16; ++kk) {
            float4 a0 = *(const float4*)&As[kk][tr << 2];
            float4 a1 = *(const float4*)&As[kk][64 + (tr << 2)];
            float4 b0 = *(const float4*)&Bs[kk][tc << 2];
            float4 b1 = *(const float4*)&Bs[kk][64 + (tc << 2)];
            float ar[8] = {a0.x,a0.y,a0.z,a0.w,a1.x,a1.y,a1.z,a1.w};
            float br[8] = {b0.x,b0.y,b0.z,b0.w,b1.x,b1.y,b1.z,b1.w};
            #pragma unroll
            for (int i = 0; i < 8; ++i)
                #pragma unroll
                for (int j = 0; j < 8; ++j) acc[i][j] = fmaf(ar[i], br[j], acc[i][j]);
        }
        __syncthreads();
    }

    #pragma unroll
    for (int ih = 0; ih < 2; ++ih)
        #pragma unroll
        for (int jh = 0; jh < 2; ++jh) {
            int o0 = bn + jh * 64 + (tc << 2);
            int which = o0 >> 10;
            int oo = o0 & 1023;
            int h = oo >> 6, d0 = oo & 63;
            int m0 = bm + ih * 64 + (tr << 2);
            int b = m0 >> 11, n0 = m0 & 2047;
            size_t bh = (size_t)b * H_ + h;
            if (which == 0) {
                #pragma unroll
                for (int i = 0; i < 4; ++i) {
                    ushort4 v;
                    v.x = f2bf(acc[ih*4+i][jh*4+0] * QSCALE);
                    v.y = f2bf(acc[ih*4+i][jh*4+1] * QSCALE);
                    v.z = f2bf(acc[ih*4+i][jh*4+2] * QSCALE);
                    v.w = f2bf(acc[ih*4+i][jh*4+3] * QSCALE);
                    *(ushort4*)&Qd[(bh * N_ + n0 + i) * D_ + d0] = v;
                }
            } else if (which == 1) {
                #pragma unroll
                for (int i = 0; i < 4; ++i) {
                    ushort4 v;
                    v.x = f2bf(acc[ih*4+i][jh*4+0]);
                    v.y = f2bf(acc[ih*4+i][jh*4+1]);
                    v.z = f2bf(acc[ih*4+i][jh*4+2]);
                    v.w = f2bf(acc[ih*4+i][jh*4+3]);
                    *(ushort4*)&Kd[(bh * N_ + n0 + i) * D_ + d0] = v;
                }
            } else {
                #pragma unroll
                for (int j = 0; j < 4; ++j) {
                    ushort4 v;
                    v.x = f2bf(acc[ih*4+0][jh*4+j]);
                    v.y = f2bf(acc[ih*4+1][jh*4+j]);
                    v.z = f2bf(acc[ih*4+2][jh*4+j]);
                    v.w = f2bf(acc[ih*4+3][jh*4+j]);
                    *(ushort4*)&Vt[(bh * D_ + d0 + j) * N_ + n0] = v;
                }
            }
        }
}

// ---------------- MFMA flash attention ----------------
// A-frag (16x16x32): row = lane&15, k = 8*(lane>>4)+e ; B-frag: col = lane&15, same k
// C/D: col = lane&15, row = 4*(lane>>4)+reg   [verified layout, learn_hip m89/m91]
__global__ __launch_bounds__(256)
void attn_mfma(const unsigned short* __restrict__ Qd, const unsigned short* __restrict__ Kd,
               const unsigned short* __restrict__ Vt, float* __restrict__ AO)
{
    __shared__ __align__(16) unsigned char KsB[2][64 * 128];  // K tile  [key][d] bf16, swz
    __shared__ __align__(16) unsigned char VtB[2][64 * 128];  // V^T tile [d][key] bf16, swz
    __shared__ __align__(16) unsigned char Pb[4][16 * 128];   // per-wave P [q][key] bf16, swz

    const int t    = threadIdx.x;
    const int lane = t & 63;
    const int w    = t >> 6;
    const int g    = lane >> 4;
    const int c    = lane & 15;
    const int cx   = c & 7;

    // bijective XCD swizzle: each XCD gets 4 consecutive bh (2MB KV -> L2-resident)
    int flat = blockIdx.x;
    int work = (flat & 7) * 128 + (flat >> 3);
    const int bh = work >> 5;
    const int qt = work & 31;
    const int b  = bh >> 4, h = bh & 15;
    const int q0 = qt * 64;

    const unsigned short* Kp  = Kd + (size_t)bh * N_ * D_;
    const unsigned short* Vp  = Vt + (size_t)bh * D_ * N_;

    // Q B-fragments: per-lane 16B global loads (q = q0 + w*16 + c, d = 32s + 8g + e)
    const unsigned short* qp = Qd + ((size_t)bh * N_ + q0 + w * 16 + c) * D_;
    bf16x8 qf0 = *(const bf16x8*)(qp + 8 * g);
    bf16x8 qf1 = *(const bf16x8*)(qp + 32 + 8 * g);

    float m_run = -1e30f, l_run = 0.f;
    f32x4 oc[4];
    f32x4 zero = {0.f, 0.f, 0.f, 0.f};
    #pragma unroll
    for (int dc = 0; dc < 4; ++dc) oc[dc] = zero;

    auto stage = [&](int nb, int kt) {
        const int kv0 = kt * KVB;
        const unsigned char* kg = (const unsigned char*)(Kp + (size_t)kv0 * D_);
        const unsigned char* vg = (const unsigned char*)Vp;
        #pragma unroll
        for (int i = 0; i < 2; ++i) {
            int gid = w * 128 + i * 64 + lane;
            int r = gid >> 3, p = gid & 7;
            async16(kg + r * 128 + ((p ^ (r & 7)) << 4),
                    KsB[nb] + (w * 128 + i * 64) * 16);
        }
        #pragma unroll
        for (int i = 0; i < 2; ++i) {
            int gid = w * 128 + i * 64 + lane;
            int d = gid >> 3, p = gid & 7;
            async16(vg + ((size_t)d * N_ + kv0) * 2 + ((p ^ (d & 7)) << 4),
                    VtB[nb] + (w * 128 + i * 64) * 16);
        }
    };

    int cur = 0;
    stage(0, 0);
    __syncthreads();

    for (int kt = 0; kt < NTILES; ++kt) {
        if (kt + 1 < NTILES) stage(cur ^ 1, kt + 1);

        // ---- S^T = K * Q^T  (rows = keys 16t+4g+r, cols = q = c) ----
        const unsigned char* kbase = KsB[cur];
        f32x4 st[4];
        #pragma unroll
        for (int tt = 0; tt < 4; ++tt) st[tt] = zero;
        #pragma unroll
        for (int s = 0; s < 2; ++s) {
            bf16x8 qf = s ? qf1 : qf0;
            #pragma unroll
            for (int tt = 0; tt < 4; ++tt) {
                bf16x8 a = *(const bf16x8*)(kbase + (tt * 16 + c) * 128 + (((4 * s + g) ^ cx) << 4));
                st[tt] = __builtin_amdgcn_mfma_f32_16x16x32_bf16(a, qf, st[tt], 0, 0, 0);
            }
        }

        // ---- online softmax over this tile's 64 keys (column q = c) ----
        float mx = st[0][0];
        #pragma unroll
        for (int tt = 0; tt < 4; ++tt)
            #pragma unroll
            for (int r = 0; r < 4; ++r) mx = fmaxf(mx, st[tt][r]);
        mx = fmaxf(mx, __shfl_xor(mx, 16));
        mx = fmaxf(mx, __shfl_xor(mx, 32));
        float nm   = fmaxf(m_run, mx);
        float corr = exp2f(m_run - nm);
        float ts = 0.f;
        #pragma unroll
        for (int tt = 0; tt < 4; ++tt)
            #pragma unroll
            for (int r = 0; r < 4; ++r) {
                float p = exp2f(st[tt][r] - nm);
                st[tt][r] = p;
                ts += p;
            }
        ts += __shfl_xor(ts, 16);
        ts += __shfl_xor(ts, 32);
        l_run = l_run * corr + ts;
        m_run = nm;
        #pragma unroll
        for (int dc = 0; dc < 4; ++dc) oc[dc] *= corr;

        // ---- pack P (truncate to bf16) into wave-private LDS [q=c][key] ----
        unsigned char* pw = Pb[w] + c * 128;
        #pragma unroll
        for (int tt = 0; tt < 4; ++tt) {
            unsigned int lo = __byte_perm(__float_as_uint(st[tt][0]), __float_as_uint(st[tt][1]), 0x7632);
            unsigned int hi = __byte_perm(__float_as_uint(st[tt][2]), __float_as_uint(st[tt][3]), 0x7632);
            int gran = 2 * tt + (g >> 1);
            unsigned int* dst = (unsigned int*)(pw + ((gran ^ cx) << 4) + 8 * (g & 1));
            dst[0] = lo;
            dst[1] = hi;
        }

        // ---- out^T += V^T * P  (rows d = dc*16+4g+r, cols q = c) ----
        const unsigned char* vb = VtB[cur];
        const unsigned char* prd = Pb[w] + c * 128;
        bf16x8 pb0 = *(const bf16x8*)(prd + ((g ^ cx) << 4));
        bf16x8 pb1 = *(const bf16x8*)(prd + (((4 + g) ^ cx) << 4));
        #pragma unroll
        for (int dc = 0; dc < 4; ++dc) {
            const unsigned char* vrow = vb + (dc * 16 + c) * 128;
            bf16x8 a0 = *(const bf16x8*)(vrow + ((g ^ cx) << 4));
            bf16x8 a1 = *(const bf16x8*)(vrow + (((4 + g) ^ cx) << 4));
            oc[dc] = __builtin_amdgcn_mfma_f32_16x16x32_bf16(a0, pb0, oc[dc], 0, 0, 0);
            oc[dc] = __builtin_amdgcn_mfma_f32_16x16x32_bf16(a1, pb1, oc[dc], 0, 0, 0);
        }

        __syncthreads();   // drains vmcnt (stage done) + protects buffer swap
        cur ^= 1;
    }

    // ---- epilogue: normalize, write AO[b][q][h*64+d] f32 ----
    float inv = 1.0f / l_run;
    int q = q0 + w * 16 + c;
    float* aop = AO + ((size_t)b * N_ + q) * C_ + h * D_;
    #pragma unroll
    for (int dc = 0; dc < 4; ++dc) {
        float4 o = make_float4(oc[dc][0] * inv, oc[dc][1] * inv, oc[dc][2] * inv, oc[dc][3] * inv);
        *(float4*)(aop + dc * 16 + 4 * g) = o;
    }
}

// ---------------- Proj GEMM + bias (f32 SIMT) ----------------
__global__ __launch_bounds__(256)
void proj_gemm(const float* __restrict__ A, const float* __restrict__ W,
               const float* __restrict__ bias, float* __restrict__ Out)
{
    __shared__ __align__(16) float As[16][128];
    __shared__ __align__(16) float Bs[16][128];
    const int t  = threadIdx.x;
    const int tr = t >> 4, tc = t & 15;
    const int bm = blockIdx.y * 128;
    const int bn = blockIdx.x * 128;
    constexpr int K = C_;

    float acc[8][8];
    #pragma unroll
    for (int i = 0; i < 8; ++i)
        #pragma unroll
        for (int j = 0; j < 8; ++j) acc[i][j] = 0.f;

    for (int k0 = 0; k0 < K; k0 += 16) {
        #pragma unroll
        for (int qq = 0; qq < 2; ++qq) {
            int id = t + qq * 256;
            int r  = id >> 2;
            int c4 = (id & 3) << 2;
            float4 va = *(const float4*)(A + (size_t)(bm + r) * K + k0 + c4);
            As[c4+0][r] = va.x; As[c4+1][r] = va.y; As[c4+2][r] = va.z; As[c4+3][r] = va.w;
            float4 vb = *(const float4*)(W + (size_t)(bn + r) * K + k0 + c4);
            Bs[c4+0][r] = vb.x; Bs[c4+1][r] = vb.y; Bs[c4+2][r] = vb.z; Bs[c4+3][r] = vb.w;
        }
        __syncthreads();
        #pragma unroll
        for (int kk = 0; kk < 16; ++kk) {
            float4 a0 = *(const float4*)&As[kk][tr << 2];
            float4 a1 = *(const float4*)&As[kk][64 + (tr << 2)];
            float4 b0 = *(const float4*)&Bs[kk][tc << 2];
            float4 b1 = *(const float4*)&Bs[kk][64 + (tc << 2)];
            float ar[8] = {a0.x,a0.y,a0.z,a0.w,a1.x,a1.y,a1.z,a1.w};
            float br[8] = {b0.x,b0.y,b0.z,b0.w,b1.x,b1.y,b1.z,b1.w};
            #pragma unroll
            for (int i = 0; i < 8; ++i)
                #pragma unroll
                for (int j = 0; j < 8; ++j) acc[i][j] = fmaf(ar[i], br[j], acc[i][j]);
        }
        __syncthreads();
    }

    #pragma unroll
    for (int ih = 0; ih < 2; ++ih)
        #pragma unroll
        for (int jh = 0; jh < 2; ++jh) {
            int o0 = bn + jh * 64 + (tc << 2);
            float4 bb = *(const float4*)&bias[o0];
            #pragma unroll
            for (int i = 0; i < 4; ++i) {
                int m = bm + ih * 64 + (tr << 2) + i;
                float4 v;
                v.x = acc[ih*4+i][jh*4+0] + bb.x;
                v.y = acc[ih*4+i][jh*4+1] + bb.y;
                v.z = acc[ih*4+i][jh*4+2] + bb.z;
                v.w = acc[ih*4+i][jh*4+3] + bb.w;
                *(float4*)&Out[(size_t)m * C_ + o0] = v;
            }
        }
}

extern "C" void kernel_launch(void* const* d_in, const int* in_sizes, int n_in,
                              void* d_out, int out_size, void* d_ws, size_t ws_size,
                              hipStream_t stream) {
    const float* x      = (const float*)d_in[0];
    const float* w_qkv  = (const float*)d_in[1];
    const float* w_proj = (const float*)d_in[2];
    const float* b_proj = (const float*)d_in[3];
    float* out = (float*)d_out;

    const size_t hd = (size_t)B_ * H_ * N_ * D_;   // 4,194,304 elems
    unsigned short* Qd = (unsigned short*)d_ws;
    unsigned short* Kd = Qd + hd;
    unsigned short* Vt = Kd + hd;
    float* AO = (float*)(Vt + hd);                  // [B,N,C] f32

    qkv_gemm<<<dim3(O3 / 128, M_ / 128), 256, 0, stream>>>(x, w_qkv, Qd, Kd, Vt);
    attn_mfma<<<dim3(1024), 256, 0, stream>>>(Qd, Kd, Vt, AO);
    proj_gemm<<<dim3(C_ / 128, M_ / 128), 256, 0, stream>>>(AO, w_proj, b_proj, out);
}

// Round 3
// 189.781 us; speedup vs baseline: 5.4979x; 2.7782x over previous
//
#include <hip/hip_runtime.h>

// CustomAttention: x[2,2048,1024] f32, w_qkv[3072,1024], w_proj[1024,1024], b_proj[1024]
// Round 3: f16 MFMA GEMMs (m97-style 128x128/BK32 global_load_lds pipeline) +
//          bf16 MFMA flash attention (unchanged from round 2, epilogue -> f16 AO).
//   k0: convert_f16: x, w_qkv, w_proj f32 -> f16 (one pass)
//   k1: gemm_f16<0>: qkv -> Qd bf16 (scaled 0.125*log2e), Kd bf16, Vt bf16 [bh][d][n]
//   k2: attn_mfma (bf16 MFMA flash) -> AO f16 [b][n][C]
//   k3: gemm_f16<1>: proj + bias -> d_out f32

constexpr int B_ = 2, N_ = 2048, C_ = 1024, H_ = 16, D_ = 64;
constexpr int M_ = B_ * N_;   // 4096
constexpr int O3 = 3 * C_;    // 3072
constexpr int KVB = 64;
constexpr int NTILES = N_ / KVB;   // 32

typedef short bf16x8 __attribute__((ext_vector_type(8)));
typedef _Float16 half8 __attribute__((ext_vector_type(8)));
typedef _Float16 half4v __attribute__((ext_vector_type(4)));
typedef float f32x4  __attribute__((ext_vector_type(4)));

__device__ __forceinline__ unsigned short f2bf(float f) {
    unsigned int u = __float_as_uint(f);
    unsigned int r = (u + 0x7FFFu + ((u >> 16) & 1u)) >> 16;
    return (unsigned short)r;
}

__device__ __forceinline__ void async16(const void* g, void* l) {
    __builtin_amdgcn_global_load_lds(
        (const __attribute__((address_space(1))) unsigned int*)g,
        (__attribute__((address_space(3))) unsigned int*)l, 16, 0, 0);
}

// ---------------- f32 -> f16 convert (x | w_qkv | w_proj) ----------------
constexpr size_t XN  = (size_t)M_ * C_;        // 4,194,304
constexpr size_t WQN = (size_t)O3 * C_;        // 3,145,728
constexpr size_t WPN = (size_t)C_ * C_;        // 1,048,576

__global__ __launch_bounds__(256)
void convert_f16(const float* __restrict__ x, const float* __restrict__ wq,
                 const float* __restrict__ wp, _Float16* __restrict__ dst)
{
    size_t i = ((size_t)blockIdx.x * 256 + threadIdx.x) * 8;
    const float* src;
    size_t off;
    if (i < XN)            { src = x;  off = i; }
    else if (i < XN + WQN) { src = wq; off = i - XN; }
    else                   { src = wp; off = i - XN - WQN; }
    float4 a = *(const float4*)(src + off);
    float4 b = *(const float4*)(src + off + 4);
    half8 h;
    h[0] = (_Float16)a.x; h[1] = (_Float16)a.y; h[2] = (_Float16)a.z; h[3] = (_Float16)a.w;
    h[4] = (_Float16)b.x; h[5] = (_Float16)b.y; h[6] = (_Float16)b.z; h[7] = (_Float16)b.w;
    *(half8*)(dst + i) = h;
}

// ---------------- f16 MFMA GEMM (128x128 tile, BK=32, dbuf global_load_lds) ----
// LDS layout per tile: [ks(0..3)][row(0..127)][16B] — ds_read_b128 at exact bank floor.
// Frags (16x16x32): A row=lane&15,k=8*(lane>>4)+e ; B col=lane&15 same k ;
// C/D col=lane&15, row=4*(lane>>4)+reg.
// MODE 0: qkv epilogue (scatter Q/K bf16 row-major, Vt bf16 [d][n]).
// MODE 1: proj epilogue (bias + f32 out).
template<int MODE>
__global__ __launch_bounds__(256)
void gemm_f16(const _Float16* __restrict__ Ag, const _Float16* __restrict__ Bg,
              unsigned short* __restrict__ Qd, unsigned short* __restrict__ Kd,
              unsigned short* __restrict__ Vt,
              const float* __restrict__ bias, float* __restrict__ Out)
{
    __shared__ __align__(16) unsigned char Ab[2][8192];
    __shared__ __align__(16) unsigned char Bb[2][8192];

    const int t    = threadIdx.x;
    const int lane = t & 63;
    const int w    = t >> 6;
    const int g    = lane >> 4;
    const int c    = lane & 15;
    const int wm   = w >> 1, wn = w & 1;
    const int bm   = blockIdx.y * 128;
    const int bn   = blockIdx.x * 128;
    constexpr int K = C_;

    f32x4 acc[4][4];
    f32x4 zero = {0.f, 0.f, 0.f, 0.f};
    #pragma unroll
    for (int mi = 0; mi < 4; ++mi)
        #pragma unroll
        for (int ni = 0; ni < 4; ++ni) acc[mi][ni] = zero;

    auto stage = [&](int buf, int k0) {
        #pragma unroll
        for (int i = 0; i < 2; ++i) {
            int id  = t + 256 * i;       // cell = [ks][row]
            int ks  = id >> 7;
            int row = id & 127;
            int ldsb = (w * 64 + i * 256) * 16;
            async16(Ag + (size_t)(bm + row) * K + k0 + 8 * ks, &Ab[buf][ldsb]);
            async16(Bg + (size_t)(bn + row) * K + k0 + 8 * ks, &Bb[buf][ldsb]);
        }
    };

    stage(0, 0);
    __syncthreads();
    int cur = 0;

    for (int k0 = 0; k0 < K; k0 += 32) {
        if (k0 + 32 < K) stage(cur ^ 1, k0 + 32);

        const unsigned char* Abase = &Ab[cur][g * 2048];
        const unsigned char* Bbase = &Bb[cur][g * 2048];
        half8 af[4], bf[4];
        #pragma unroll
        for (int mi = 0; mi < 4; ++mi)
            af[mi] = *(const half8*)(Abase + (wm * 64 + mi * 16 + c) * 16);
        #pragma unroll
        for (int ni = 0; ni < 4; ++ni)
            bf[ni] = *(const half8*)(Bbase + (wn * 64 + ni * 16 + c) * 16);
        #pragma unroll
        for (int mi = 0; mi < 4; ++mi)
            #pragma unroll
            for (int ni = 0; ni < 4; ++ni)
                acc[mi][ni] = __builtin_amdgcn_mfma_f32_16x16x32_f16(af[mi], bf[ni], acc[mi][ni], 0, 0, 0);

        __syncthreads();
        cur ^= 1;
    }

    if constexpr (MODE == 0) {
        // scatter epilogue: o = which*1024 + h*64 + d
        constexpr float QSCALE = 0.125f * 1.4426950408889634f;   // D^-0.5 * log2(e)
        const int which = bn >> 10;
        const int h  = (((bn & 1023) + wn * 64) >> 6);
        const int b  = (bm + wm * 64) >> 11;
        const int n0 = (bm + wm * 64) & 2047;
        const size_t bh = (size_t)b * H_ + h;
        if (which == 0) {
            unsigned short* base = Qd + (bh * N_) * D_;
            #pragma unroll
            for (int mi = 0; mi < 4; ++mi)
                #pragma unroll
                for (int ni = 0; ni < 4; ++ni)
                    #pragma unroll
                    for (int r = 0; r < 4; ++r)
                        base[(size_t)(n0 + mi * 16 + 4 * g + r) * D_ + ni * 16 + c] =
                            f2bf(acc[mi][ni][r] * QSCALE);
        } else if (which == 1) {
            unsigned short* base = Kd + (bh * N_) * D_;
            #pragma unroll
            for (int mi = 0; mi < 4; ++mi)
                #pragma unroll
                for (int ni = 0; ni < 4; ++ni)
                    #pragma unroll
                    for (int r = 0; r < 4; ++r)
                        base[(size_t)(n0 + mi * 16 + 4 * g + r) * D_ + ni * 16 + c] =
                            f2bf(acc[mi][ni][r]);
        } else {
            unsigned short* base = Vt + (bh * D_) * (size_t)N_;
            #pragma unroll
            for (int mi = 0; mi < 4; ++mi)
                #pragma unroll
                for (int ni = 0; ni < 4; ++ni) {
                    ushort4 v;
                    v.x = f2bf(acc[mi][ni][0]);
                    v.y = f2bf(acc[mi][ni][1]);
                    v.z = f2bf(acc[mi][ni][2]);
                    v.w = f2bf(acc[mi][ni][3]);
                    *(ushort4*)&base[(size_t)(ni * 16 + c) * N_ + n0 + mi * 16 + 4 * g] = v;
                }
        }
    } else {
        const int m0 = bm + wm * 64;
        const int o0 = bn + wn * 64;
        #pragma unroll
        for (int ni = 0; ni < 4; ++ni) {
            float bb = bias[o0 + ni * 16 + c];
            #pragma unroll
            for (int mi = 0; mi < 4; ++mi)
                #pragma unroll
                for (int r = 0; r < 4; ++r)
                    Out[(size_t)(m0 + mi * 16 + 4 * g + r) * C_ + o0 + ni * 16 + c] =
                        acc[mi][ni][r] + bb;
        }
    }
}

// ---------------- MFMA flash attention (bf16, unchanged; epilogue -> f16) ------
__global__ __launch_bounds__(256)
void attn_mfma(const unsigned short* __restrict__ Qd, const unsigned short* __restrict__ Kd,
               const unsigned short* __restrict__ Vt, _Float16* __restrict__ AO)
{
    __shared__ __align__(16) unsigned char KsB[2][64 * 128];  // K tile  [key][d] bf16, swz
    __shared__ __align__(16) unsigned char VtB[2][64 * 128];  // V^T tile [d][key] bf16, swz
    __shared__ __align__(16) unsigned char Pb[4][16 * 128];   // per-wave P [q][key] bf16, swz

    const int t    = threadIdx.x;
    const int lane = t & 63;
    const int w    = t >> 6;
    const int g    = lane >> 4;
    const int c    = lane & 15;
    const int cx   = c & 7;

    // bijective XCD swizzle: each XCD gets 4 consecutive bh (2MB KV -> L2-resident)
    int flat = blockIdx.x;
    int work = (flat & 7) * 128 + (flat >> 3);
    const int bh = work >> 5;
    const int qt = work & 31;
    const int b  = bh >> 4, h = bh & 15;
    const int q0 = qt * 64;

    const unsigned short* Kp  = Kd + (size_t)bh * N_ * D_;
    const unsigned short* Vp  = Vt + (size_t)bh * D_ * N_;

    const unsigned short* qp = Qd + ((size_t)bh * N_ + q0 + w * 16 + c) * D_;
    bf16x8 qf0 = *(const bf16x8*)(qp + 8 * g);
    bf16x8 qf1 = *(const bf16x8*)(qp + 32 + 8 * g);

    float m_run = -1e30f, l_run = 0.f;
    f32x4 oc[4];
    f32x4 zero = {0.f, 0.f, 0.f, 0.f};
    #pragma unroll
    for (int dc = 0; dc < 4; ++dc) oc[dc] = zero;

    auto stage = [&](int nb, int kt) {
        const int kv0 = kt * KVB;
        const unsigned char* kg = (const unsigned char*)(Kp + (size_t)kv0 * D_);
        const unsigned char* vg = (const unsigned char*)Vp;
        #pragma unroll
        for (int i = 0; i < 2; ++i) {
            int gid = w * 128 + i * 64 + lane;
            int r = gid >> 3, p = gid & 7;
            async16(kg + r * 128 + ((p ^ (r & 7)) << 4),
                    KsB[nb] + (w * 128 + i * 64) * 16);
        }
        #pragma unroll
        for (int i = 0; i < 2; ++i) {
            int gid = w * 128 + i * 64 + lane;
            int d = gid >> 3, p = gid & 7;
            async16(vg + ((size_t)d * N_ + kv0) * 2 + ((p ^ (d & 7)) << 4),
                    VtB[nb] + (w * 128 + i * 64) * 16);
        }
    };

    int cur = 0;
    stage(0, 0);
    __syncthreads();

    for (int kt = 0; kt < NTILES; ++kt) {
        if (kt + 1 < NTILES) stage(cur ^ 1, kt + 1);

        // ---- S^T = K * Q^T ----
        const unsigned char* kbase = KsB[cur];
        f32x4 st[4];
        #pragma unroll
        for (int tt = 0; tt < 4; ++tt) st[tt] = zero;
        #pragma unroll
        for (int s = 0; s < 2; ++s) {
            bf16x8 qf = s ? qf1 : qf0;
            #pragma unroll
            for (int tt = 0; tt < 4; ++tt) {
                bf16x8 a = *(const bf16x8*)(kbase + (tt * 16 + c) * 128 + (((4 * s + g) ^ cx) << 4));
                st[tt] = __builtin_amdgcn_mfma_f32_16x16x32_bf16(a, qf, st[tt], 0, 0, 0);
            }
        }

        // ---- online softmax ----
        float mx = st[0][0];
        #pragma unroll
        for (int tt = 0; tt < 4; ++tt)
            #pragma unroll
            for (int r = 0; r < 4; ++r) mx = fmaxf(mx, st[tt][r]);
        mx = fmaxf(mx, __shfl_xor(mx, 16));
        mx = fmaxf(mx, __shfl_xor(mx, 32));
        float nm   = fmaxf(m_run, mx);
        float corr = exp2f(m_run - nm);
        float ts = 0.f;
        #pragma unroll
        for (int tt = 0; tt < 4; ++tt)
            #pragma unroll
            for (int r = 0; r < 4; ++r) {
                float p = exp2f(st[tt][r] - nm);
                st[tt][r] = p;
                ts += p;
            }
        ts += __shfl_xor(ts, 16);
        ts += __shfl_xor(ts, 32);
        l_run = l_run * corr + ts;
        m_run = nm;
        #pragma unroll
        for (int dc = 0; dc < 4; ++dc) oc[dc] *= corr;

        // ---- pack P -> wave-private LDS ----
        unsigned char* pw = Pb[w] + c * 128;
        #pragma unroll
        for (int tt = 0; tt < 4; ++tt) {
            unsigned int lo = __byte_perm(__float_as_uint(st[tt][0]), __float_as_uint(st[tt][1]), 0x7632);
            unsigned int hi = __byte_perm(__float_as_uint(st[tt][2]), __float_as_uint(st[tt][3]), 0x7632);
            int gran = 2 * tt + (g >> 1);
            unsigned int* dst = (unsigned int*)(pw + ((gran ^ cx) << 4) + 8 * (g & 1));
            dst[0] = lo;
            dst[1] = hi;
        }

        // ---- out^T += V^T * P ----
        const unsigned char* vb = VtB[cur];
        const unsigned char* prd = Pb[w] + c * 128;
        bf16x8 pb0 = *(const bf16x8*)(prd + ((g ^ cx) << 4));
        bf16x8 pb1 = *(const bf16x8*)(prd + (((4 + g) ^ cx) << 4));
        #pragma unroll
        for (int dc = 0; dc < 4; ++dc) {
            const unsigned char* vrow = vb + (dc * 16 + c) * 128;
            bf16x8 a0 = *(const bf16x8*)(vrow + ((g ^ cx) << 4));
            bf16x8 a1 = *(const bf16x8*)(vrow + (((4 + g) ^ cx) << 4));
            oc[dc] = __builtin_amdgcn_mfma_f32_16x16x32_bf16(a0, pb0, oc[dc], 0, 0, 0);
            oc[dc] = __builtin_amdgcn_mfma_f32_16x16x32_bf16(a1, pb1, oc[dc], 0, 0, 0);
        }

        __syncthreads();
        cur ^= 1;
    }

    // ---- epilogue: normalize, write AO f16 [b][q][h*64+d] ----
    float inv = 1.0f / l_run;
    int q = q0 + w * 16 + c;
    _Float16* aop = AO + ((size_t)b * N_ + q) * C_ + h * D_;
    #pragma unroll
    for (int dc = 0; dc < 4; ++dc) {
        half4v o;
        o[0] = (_Float16)(oc[dc][0] * inv);
        o[1] = (_Float16)(oc[dc][1] * inv);
        o[2] = (_Float16)(oc[dc][2] * inv);
        o[3] = (_Float16)(oc[dc][3] * inv);
        *(half4v*)(aop + dc * 16 + 4 * g) = o;
    }
}

extern "C" void kernel_launch(void* const* d_in, const int* in_sizes, int n_in,
                              void* d_out, int out_size, void* d_ws, size_t ws_size,
                              hipStream_t stream) {
    const float* x      = (const float*)d_in[0];
    const float* w_qkv  = (const float*)d_in[1];
    const float* w_proj = (const float*)d_in[2];
    const float* b_proj = (const float*)d_in[3];
    float* out = (float*)d_out;

    const size_t hd = (size_t)B_ * H_ * N_ * D_;   // 4,194,304 elems
    unsigned short* Qd = (unsigned short*)d_ws;
    unsigned short* Kd = Qd + hd;
    unsigned short* Vt = Kd + hd;
    _Float16* AO  = (_Float16*)(Vt + hd);          // [B,N,C] f16
    _Float16* x16 = AO + hd;                       // [4096][1024]
    _Float16* wq16 = x16 + XN;                     // [3072][1024]
    _Float16* wp16 = wq16 + WQN;                   // [1024][1024]

    convert_f16<<<4096, 256, 0, stream>>>(x, w_qkv, w_proj, x16);
    gemm_f16<0><<<dim3(O3 / 128, M_ / 128), 256, 0, stream>>>(
        x16, wq16, Qd, Kd, Vt, nullptr, nullptr);
    attn_mfma<<<dim3(1024), 256, 0, stream>>>(Qd, Kd, Vt, AO);
    gemm_f16<1><<<dim3(C_ / 128, M_ / 128), 256, 0, stream>>>(
        AO, wp16, nullptr, nullptr, nullptr, b_proj, out);
}

// Round 4
// 178.342 us; speedup vs baseline: 5.8506x; 1.0641x over previous
//
#include <hip/hip_runtime.h>

// CustomAttention: x[2,2048,1024] f32, w_qkv[3072,1024], w_proj[1024,1024], b_proj[1024]
// Round 4: attention restructured to 8-wave/512-thread blocks (128 q rows),
//          defer-max online softmax, setprio around MFMA. f16 MFMA GEMMs unchanged.
//   k0: convert_f16: x, w_qkv, w_proj f32 -> f16
//   k1: gemm_f16<0>: qkv -> Qd bf16 (scaled 0.125*log2e), Kd bf16, Vt bf16 [bh][d][n]
//   k2: attn_mfma (bf16 MFMA flash, 8 waves) -> AO f16 [b][n][C]
//   k3: gemm_f16<1>: proj + bias -> d_out f32

constexpr int B_ = 2, N_ = 2048, C_ = 1024, H_ = 16, D_ = 64;
constexpr int M_ = B_ * N_;   // 4096
constexpr int O3 = 3 * C_;    // 3072
constexpr int KVB = 64;
constexpr int NTILES = N_ / KVB;   // 32

typedef short bf16x8 __attribute__((ext_vector_type(8)));
typedef _Float16 half8 __attribute__((ext_vector_type(8)));
typedef _Float16 half4v __attribute__((ext_vector_type(4)));
typedef float f32x4  __attribute__((ext_vector_type(4)));

__device__ __forceinline__ unsigned short f2bf(float f) {
    unsigned int u = __float_as_uint(f);
    unsigned int r = (u + 0x7FFFu + ((u >> 16) & 1u)) >> 16;
    return (unsigned short)r;
}

__device__ __forceinline__ void async16(const void* g, void* l) {
    __builtin_amdgcn_global_load_lds(
        (const __attribute__((address_space(1))) unsigned int*)g,
        (__attribute__((address_space(3))) unsigned int*)l, 16, 0, 0);
}

// ---------------- f32 -> f16 convert (x | w_qkv | w_proj) ----------------
constexpr size_t XN  = (size_t)M_ * C_;        // 4,194,304
constexpr size_t WQN = (size_t)O3 * C_;        // 3,145,728
constexpr size_t WPN = (size_t)C_ * C_;        // 1,048,576

__global__ __launch_bounds__(256)
void convert_f16(const float* __restrict__ x, const float* __restrict__ wq,
                 const float* __restrict__ wp, _Float16* __restrict__ dst)
{
    size_t i = ((size_t)blockIdx.x * 256 + threadIdx.x) * 8;
    const float* src;
    size_t off;
    if (i < XN)            { src = x;  off = i; }
    else if (i < XN + WQN) { src = wq; off = i - XN; }
    else                   { src = wp; off = i - XN - WQN; }
    float4 a = *(const float4*)(src + off);
    float4 b = *(const float4*)(src + off + 4);
    half8 h;
    h[0] = (_Float16)a.x; h[1] = (_Float16)a.y; h[2] = (_Float16)a.z; h[3] = (_Float16)a.w;
    h[4] = (_Float16)b.x; h[5] = (_Float16)b.y; h[6] = (_Float16)b.z; h[7] = (_Float16)b.w;
    *(half8*)(dst + i) = h;
}

// ---------------- f16 MFMA GEMM (128x128 tile, BK=32, dbuf global_load_lds) ----
template<int MODE>
__global__ __launch_bounds__(256)
void gemm_f16(const _Float16* __restrict__ Ag, const _Float16* __restrict__ Bg,
              unsigned short* __restrict__ Qd, unsigned short* __restrict__ Kd,
              unsigned short* __restrict__ Vt,
              const float* __restrict__ bias, float* __restrict__ Out)
{
    __shared__ __align__(16) unsigned char Ab[2][8192];
    __shared__ __align__(16) unsigned char Bb[2][8192];

    const int t    = threadIdx.x;
    const int lane = t & 63;
    const int w    = t >> 6;
    const int g    = lane >> 4;
    const int c    = lane & 15;
    const int wm   = w >> 1, wn = w & 1;
    const int bm   = blockIdx.y * 128;
    const int bn   = blockIdx.x * 128;
    constexpr int K = C_;

    f32x4 acc[4][4];
    f32x4 zero = {0.f, 0.f, 0.f, 0.f};
    #pragma unroll
    for (int mi = 0; mi < 4; ++mi)
        #pragma unroll
        for (int ni = 0; ni < 4; ++ni) acc[mi][ni] = zero;

    auto stage = [&](int buf, int k0) {
        #pragma unroll
        for (int i = 0; i < 2; ++i) {
            int id  = t + 256 * i;       // cell = [ks][row]
            int ks  = id >> 7;
            int row = id & 127;
            int ldsb = (w * 64 + i * 256) * 16;
            async16(Ag + (size_t)(bm + row) * K + k0 + 8 * ks, &Ab[buf][ldsb]);
            async16(Bg + (size_t)(bn + row) * K + k0 + 8 * ks, &Bb[buf][ldsb]);
        }
    };

    stage(0, 0);
    __syncthreads();
    int cur = 0;

    for (int k0 = 0; k0 < K; k0 += 32) {
        if (k0 + 32 < K) stage(cur ^ 1, k0 + 32);

        const unsigned char* Abase = &Ab[cur][g * 2048];
        const unsigned char* Bbase = &Bb[cur][g * 2048];
        half8 af[4], bf[4];
        #pragma unroll
        for (int mi = 0; mi < 4; ++mi)
            af[mi] = *(const half8*)(Abase + (wm * 64 + mi * 16 + c) * 16);
        #pragma unroll
        for (int ni = 0; ni < 4; ++ni)
            bf[ni] = *(const half8*)(Bbase + (wn * 64 + ni * 16 + c) * 16);
        #pragma unroll
        for (int mi = 0; mi < 4; ++mi)
            #pragma unroll
            for (int ni = 0; ni < 4; ++ni)
                acc[mi][ni] = __builtin_amdgcn_mfma_f32_16x16x32_f16(af[mi], bf[ni], acc[mi][ni], 0, 0, 0);

        __syncthreads();
        cur ^= 1;
    }

    if constexpr (MODE == 0) {
        constexpr float QSCALE = 0.125f * 1.4426950408889634f;   // D^-0.5 * log2(e)
        const int which = bn >> 10;
        const int h  = (((bn & 1023) + wn * 64) >> 6);
        const int b  = (bm + wm * 64) >> 11;
        const int n0 = (bm + wm * 64) & 2047;
        const size_t bh = (size_t)b * H_ + h;
        if (which == 0) {
            unsigned short* base = Qd + (bh * N_) * D_;
            #pragma unroll
            for (int mi = 0; mi < 4; ++mi)
                #pragma unroll
                for (int ni = 0; ni < 4; ++ni)
                    #pragma unroll
                    for (int r = 0; r < 4; ++r)
                        base[(size_t)(n0 + mi * 16 + 4 * g + r) * D_ + ni * 16 + c] =
                            f2bf(acc[mi][ni][r] * QSCALE);
        } else if (which == 1) {
            unsigned short* base = Kd + (bh * N_) * D_;
            #pragma unroll
            for (int mi = 0; mi < 4; ++mi)
                #pragma unroll
                for (int ni = 0; ni < 4; ++ni)
                    #pragma unroll
                    for (int r = 0; r < 4; ++r)
                        base[(size_t)(n0 + mi * 16 + 4 * g + r) * D_ + ni * 16 + c] =
                            f2bf(acc[mi][ni][r]);
        } else {
            unsigned short* base = Vt + (bh * D_) * (size_t)N_;
            #pragma unroll
            for (int mi = 0; mi < 4; ++mi)
                #pragma unroll
                for (int ni = 0; ni < 4; ++ni) {
                    ushort4 v;
                    v.x = f2bf(acc[mi][ni][0]);
                    v.y = f2bf(acc[mi][ni][1]);
                    v.z = f2bf(acc[mi][ni][2]);
                    v.w = f2bf(acc[mi][ni][3]);
                    *(ushort4*)&base[(size_t)(ni * 16 + c) * N_ + n0 + mi * 16 + 4 * g] = v;
                }
        }
    } else {
        const int m0 = bm + wm * 64;
        const int o0 = bn + wn * 64;
        #pragma unroll
        for (int ni = 0; ni < 4; ++ni) {
            float bb = bias[o0 + ni * 16 + c];
            #pragma unroll
            for (int mi = 0; mi < 4; ++mi)
                #pragma unroll
                for (int r = 0; r < 4; ++r)
                    Out[(size_t)(m0 + mi * 16 + 4 * g + r) * C_ + o0 + ni * 16 + c] =
                        acc[mi][ni][r] + bb;
        }
    }
}

// ---------------- MFMA flash attention: 8 waves, 128 q rows per block ----------
// Frags (16x16x32): A row=lane&15,k=8*(lane>>4)+e ; B col=lane&15 same k ;
// C/D col=lane&15, row=4*(lane>>4)+reg.
__global__ __launch_bounds__(512)
void attn_mfma(const unsigned short* __restrict__ Qd, const unsigned short* __restrict__ Kd,
               const unsigned short* __restrict__ Vt, _Float16* __restrict__ AO)
{
    __shared__ __align__(16) unsigned char KsB[2][64 * 128];  // K tile  [key][d] bf16, swz
    __shared__ __align__(16) unsigned char VtB[2][64 * 128];  // V^T tile [d][key] bf16, swz
    __shared__ __align__(16) unsigned char Pb[8][16 * 128];   // per-wave P [q][key] bf16, swz

    const int t    = threadIdx.x;
    const int lane = t & 63;
    const int w    = t >> 6;                 // 0..7
    const int g    = lane >> 4;
    const int c    = lane & 15;
    const int cx   = c & 7;

    // bijective XCD swizzle: 512 blocks, 64 works/XCD -> 4 consecutive bh per XCD
    int flat = blockIdx.x;
    int work = (flat & 7) * 64 + (flat >> 3);
    const int bh = work >> 4;               // 0..31
    const int qt = work & 15;               // 0..15
    const int b  = bh >> 4, h = bh & 15;
    const int q0 = qt * 128;

    const unsigned short* Kp = Kd + (size_t)bh * N_ * D_;
    const unsigned short* Vp = Vt + (size_t)bh * D_ * N_;

    // Q B-fragments: per-lane 16B loads (q = q0 + w*16 + c, d = 32s + 8g + e)
    const unsigned short* qp = Qd + ((size_t)bh * N_ + q0 + w * 16 + c) * D_;
    bf16x8 qf0 = *(const bf16x8*)(qp + 8 * g);
    bf16x8 qf1 = *(const bf16x8*)(qp + 32 + 8 * g);

    // precomputed per-thread staging addresses (advance per tile)
    const int rk = t >> 3, pk = t & 7;       // K: row 0..63, granule
    const unsigned char* kSrc = (const unsigned char*)Kp + rk * 128 + ((pk ^ (rk & 7)) << 4);
    const unsigned char* vSrc = (const unsigned char*)Vp + (size_t)rk * N_ * 2 + ((pk ^ (rk & 7)) << 4);
    unsigned char* kDstA = KsB[0] + t * 16;
    unsigned char* kDstB = KsB[1] + t * 16;
    unsigned char* vDstA = VtB[0] + t * 16;
    unsigned char* vDstB = VtB[1] + t * 16;

    float m_run = -1e30f, l_run = 0.f;
    f32x4 oc[4];
    f32x4 zero = {0.f, 0.f, 0.f, 0.f};
    #pragma unroll
    for (int dc = 0; dc < 4; ++dc) oc[dc] = zero;

    async16(kSrc, kDstA);
    async16(vSrc, vDstA);
    __syncthreads();

    int cur = 0;
    for (int kt = 0; kt < NTILES; ++kt) {
        if (kt + 1 < NTILES) {
            const unsigned char* ks = kSrc + (size_t)(kt + 1) * KVB * 128;
            const unsigned char* vs = vSrc + (size_t)(kt + 1) * 128;
            async16(ks, cur ? kDstA : kDstB);
            async16(vs, cur ? vDstA : vDstB);
        }

        // ---- S^T = K * Q^T  (rows = keys, cols = q = c) ----
        const unsigned char* kbase = KsB[cur];
        f32x4 st[4];
        #pragma unroll
        for (int tt = 0; tt < 4; ++tt) st[tt] = zero;
        __builtin_amdgcn_s_setprio(1);
        #pragma unroll
        for (int s = 0; s < 2; ++s) {
            bf16x8 qf = s ? qf1 : qf0;
            #pragma unroll
            for (int tt = 0; tt < 4; ++tt) {
                bf16x8 a = *(const bf16x8*)(kbase + (tt * 16 + c) * 128 + (((4 * s + g) ^ cx) << 4));
                st[tt] = __builtin_amdgcn_mfma_f32_16x16x32_bf16(a, qf, st[tt], 0, 0, 0);
            }
        }
        __builtin_amdgcn_s_setprio(0);

        // ---- online softmax with defer-max (THR = 8 in log2 domain) ----
        float mx = st[0][0];
        #pragma unroll
        for (int tt = 0; tt < 4; ++tt)
            #pragma unroll
            for (int r = 0; r < 4; ++r) mx = fmaxf(mx, st[tt][r]);
        mx = fmaxf(mx, __shfl_xor(mx, 16));
        mx = fmaxf(mx, __shfl_xor(mx, 32));
        const bool defer = __all(mx <= m_run + 8.f);
        const float nm = defer ? m_run : fmaxf(m_run, mx);
        float ts = 0.f;
        #pragma unroll
        for (int tt = 0; tt < 4; ++tt)
            #pragma unroll
            for (int r = 0; r < 4; ++r) {
                float p = exp2f(st[tt][r] - nm);
                st[tt][r] = p;
                ts += p;
            }
        ts += __shfl_xor(ts, 16);
        ts += __shfl_xor(ts, 32);
        if (defer) {
            l_run += ts;
        } else {
            float corr = exp2f(m_run - nm);
            l_run = l_run * corr + ts;
            m_run = nm;
            #pragma unroll
            for (int dc = 0; dc < 4; ++dc) oc[dc] *= corr;
        }

        // ---- pack P (truncate to bf16) -> wave-private LDS [q=c][key] ----
        unsigned char* pw = Pb[w] + c * 128;
        #pragma unroll
        for (int tt = 0; tt < 4; ++tt) {
            unsigned int lo = __byte_perm(__float_as_uint(st[tt][0]), __float_as_uint(st[tt][1]), 0x7632);
            unsigned int hi = __byte_perm(__float_as_uint(st[tt][2]), __float_as_uint(st[tt][3]), 0x7632);
            int gran = 2 * tt + (g >> 1);
            unsigned int* dst = (unsigned int*)(pw + ((gran ^ cx) << 4) + 8 * (g & 1));
            dst[0] = lo;
            dst[1] = hi;
        }

        // ---- out^T += V^T * P  (rows d, cols q = c) ----
        const unsigned char* vb = VtB[cur];
        const unsigned char* prd = Pb[w] + c * 128;
        bf16x8 pb0 = *(const bf16x8*)(prd + ((g ^ cx) << 4));
        bf16x8 pb1 = *(const bf16x8*)(prd + (((4 + g) ^ cx) << 4));
        __builtin_amdgcn_s_setprio(1);
        #pragma unroll
        for (int dc = 0; dc < 4; ++dc) {
            const unsigned char* vrow = vb + (dc * 16 + c) * 128;
            bf16x8 a0 = *(const bf16x8*)(vrow + ((g ^ cx) << 4));
            bf16x8 a1 = *(const bf16x8*)(vrow + (((4 + g) ^ cx) << 4));
            oc[dc] = __builtin_amdgcn_mfma_f32_16x16x32_bf16(a0, pb0, oc[dc], 0, 0, 0);
            oc[dc] = __builtin_amdgcn_mfma_f32_16x16x32_bf16(a1, pb1, oc[dc], 0, 0, 0);
        }
        __builtin_amdgcn_s_setprio(0);

        __syncthreads();   // drains vmcnt (stage done) + protects buffer swap
        cur ^= 1;
    }

    // ---- epilogue: normalize, write AO f16 [b][q][h*64+d] ----
    float inv = 1.0f / l_run;
    int q = q0 + w * 16 + c;
    _Float16* aop = AO + ((size_t)b * N_ + q) * C_ + h * D_;
    #pragma unroll
    for (int dc = 0; dc < 4; ++dc) {
        half4v o;
        o[0] = (_Float16)(oc[dc][0] * inv);
        o[1] = (_Float16)(oc[dc][1] * inv);
        o[2] = (_Float16)(oc[dc][2] * inv);
        o[3] = (_Float16)(oc[dc][3] * inv);
        *(half4v*)(aop + dc * 16 + 4 * g) = o;
    }
}

extern "C" void kernel_launch(void* const* d_in, const int* in_sizes, int n_in,
                              void* d_out, int out_size, void* d_ws, size_t ws_size,
                              hipStream_t stream) {
    const float* x      = (const float*)d_in[0];
    const float* w_qkv  = (const float*)d_in[1];
    const float* w_proj = (const float*)d_in[2];
    const float* b_proj = (const float*)d_in[3];
    float* out = (float*)d_out;

    const size_t hd = (size_t)B_ * H_ * N_ * D_;   // 4,194,304 elems
    unsigned short* Qd = (unsigned short*)d_ws;
    unsigned short* Kd = Qd + hd;
    unsigned short* Vt = Kd + hd;
    _Float16* AO  = (_Float16*)(Vt + hd);          // [B,N,C] f16
    _Float16* x16 = AO + hd;                       // [4096][1024]
    _Float16* wq16 = x16 + XN;                     // [3072][1024]
    _Float16* wp16 = wq16 + WQN;                   // [1024][1024]

    convert_f16<<<4096, 256, 0, stream>>>(x, w_qkv, w_proj, x16);
    gemm_f16<0><<<dim3(O3 / 128, M_ / 128), 256, 0, stream>>>(
        x16, wq16, Qd, Kd, Vt, nullptr, nullptr);
    attn_mfma<<<dim3(512), 512, 0, stream>>>(Qd, Kd, Vt, AO);
    gemm_f16<1><<<dim3(C_ / 128, M_ / 128), 256, 0, stream>>>(
        AO, wp16, nullptr, nullptr, nullptr, b_proj, out);
}